// Round 23
// baseline (42.304 us; speedup 1.0000x reference)
//
#include <hip/hip_runtime.h>

// SimpleHybridModel via MFMA, all-transposed chaining:
//  conv1d(k=3,SAME,relu) -> SimpleRNN(16,tanh) -> dense(8,relu) -> dense(1)
//
// R23: MAX-TLP test. 2-wave blocks, wave-local 16 elems/wave, FUSED 1-chain
// loop, VGPR<=64 (launch_bounds(128,8)) -> 16 blocks x 2 waves = 32 waves/CU
// (8/SIMD, HW max) at R22's same 512 resident elems.
// Discriminating experiment: residency-model predicts flat (~39us);
// TLP-hiding predicts 31-35; chain-ILP predicts 42-46. R22 (39.1us) is the
// fallback if flat/worse.
//  - fused loop (no B2s arrays: -40 VGPR) to fit the 64-reg 8-wave budget.
//  - pad-free 20-slot layout (R22): 16 elems x 320B = 5120B/wave region,
//    10240B/block exact. SAME-padding via A-operand zeroing (A1_0 at l=0,
//    A1_19 at l=19); boundary reads hit own-wave neighbor rows (staged,
//    finite); both OOB edges (b16==0,g==0,l=0 / b16==15,g==2,l=19) redirect
//    to own-region base (staged by OWN wave -> no cross-wave uninit read).
//  - row-per-lane staging (R21): 320 rows/wave = 5 rounds; 2 overlapping
//    dwordx4 -> 4 pkrtz (dummy 1.0 rides pkrtz(f6,1.0)) -> 1 ds_write_b128.
//  - wave-local fence only (lgkmcnt(0) + sched_barrier, rule #18); no
//    __syncthreads.
// Retained: conv bias rides MFMA k=31 vs dummy-1.0 half, g==3 reads slot l,
// 2*log2e folded into A2/AU/rnn_b, rcp+exp2 tanh, packed cvts, head via MFMA.

#define BLK 128
#define LSEQ 20
#define EPW 80              // dwords per element: 20 slots * 4 (320 B)
#define WREG (16*EPW)       // 1280 dwords per wave region
#define LOG2E2 2.8853900817779268f

typedef _Float16 f16;
typedef __fp16   fp16x2 __attribute__((ext_vector_type(2)));
typedef _Float16 f16x4 __attribute__((ext_vector_type(4)));
typedef _Float16 f16x8 __attribute__((ext_vector_type(8)));
typedef float    f32x4 __attribute__((ext_vector_type(4)));

union UB128 { uint4 q; f16x8 v; };
union UB64  { f16x4 v; fp16x2 p[2]; };
union HU    { fp16x2 p; uint u; };

__global__ __launch_bounds__(BLK, 8) void hybrid_fwd(
    const float* __restrict__ x,
    const float* __restrict__ conv_w, const float* __restrict__ conv_b,
    const float* __restrict__ rnn_w,  const float* __restrict__ rnn_u,
    const float* __restrict__ rnn_b,
    const float* __restrict__ d1_w,   const float* __restrict__ d1_b,
    const float* __restrict__ out_w,  const float* __restrict__ out_b,
    float* __restrict__ out)
{
    __shared__ __align__(16) uint xs[2 * WREG];   // 10240 B exact (16 blk/CU)

    const int tid  = threadIdx.x;
    const int wave = tid >> 6, lane = tid & 63;
    const int b16  = lane & 15, g = lane >> 4;
    const long BE  = (long)blockIdx.x * 32;       // block's first elem
    uint* wb = xs + wave * WREG;                  // this wave's region

    // ---- weight fragments (VMEM latency overlaps staging) ----
    f16x8 A1;
    #pragma unroll
    for (int t = 0; t < 8; ++t) {
        float wv = conv_w[min(g * 7 + t, 20) * 16 + b16];
        float sel = (g < 3 && t < 7) ? wv
                  : ((g == 3 && t == 7) ? conv_b[b16] : 0.f);
        A1[t] = (f16)sel;
    }
    const f16x8 A1z = {};
    const f16x8 A1_0  = (g == 0) ? A1z : A1;   // l=0:  row -1 tap = 0
    const f16x8 A1_19 = (g == 2) ? A1z : A1;   // l=19: row 20 tap = 0
    f16x4 A2, AU;
    f32x4 rbp;
    #pragma unroll
    for (int t = 0; t < 4; ++t) {
        A2[t]  = (f16)(LOG2E2 * rnn_w[(4 * g + t) * 16 + b16]);
        AU[t]  = (f16)(LOG2E2 * rnn_u[(4 * g + t) * 16 + b16]);
        rbp[t] = LOG2E2 * rnn_b[4 * g + t];
    }
    f16x4 A3;
    f32x4 c3;
    #pragma unroll
    for (int t = 0; t < 4; ++t) {
        int j = 4 * g + t;
        A3[t] = (f16)(b16 < 8 ? d1_w[j * 8 + b16] : 0.f);
        c3[t] = d1_b[min(j, 7)];
    }
    float ow[4];
    #pragma unroll
    for (int r = 0; r < 4; ++r)
        ow[r] = (g < 2) ? out_w[min(4 * g + r, 7)] : 0.f;
    const float ob = out_b[0];
    const f32x4 zero4 = {0.f, 0.f, 0.f, 0.f};

    // ---- stage x: row-per-lane, 320 rows/wave = 5 rounds ----
    {
        const float* xg = x + (BE + wave * 16) * 140;
        #pragma unroll
        for (int k = 0; k < 5; ++k) {
            int rowflat = lane + 64 * k;          // 0..319
            int e = rowflat / 20;                 // elem 0..15 (magic-mul)
            int r = rowflat - e * 20;
            const float* rp = xg + e * 140 + r * 7;
            float4 v0 = *(const float4*)(rp);     // floats 0..3
            float4 v1 = *(const float4*)(rp + 3); // floats 3..6
            HU h0, h1, h2, h3;
            h0.p = __builtin_amdgcn_cvt_pkrtz(v0.x, v0.y);
            h1.p = __builtin_amdgcn_cvt_pkrtz(v0.z, v0.w);
            h2.p = __builtin_amdgcn_cvt_pkrtz(v1.y, v1.z);
            h3.p = __builtin_amdgcn_cvt_pkrtz(v1.w, 1.0f);   // dummy 1.0
            uint4 val; val.x = h0.u; val.y = h1.u; val.z = h2.u; val.w = h3.u;
            *(uint4*)(wb + e * EPW + 4 * r) = val;           // 16B aligned
        }
    }

    // ---- wave-local fence (rule #18) ----
    asm volatile("s_waitcnt lgkmcnt(0)" ::: "memory");
    __builtin_amdgcn_sched_barrier(0);

    // read ptr: tap g reads slot l-1+g (g<=2); g=3 reads slot l (bias lane)
    const int d = (g == 3) ? 0 : (g - 1);
    const uint* p0 = wb + b16 * EPW + 4 * d;
    const uint* a0   = (b16 == 0  && g == 0) ? wb : p0;         // l=0 edge
    const uint* aL19 = (b16 == 15 && g == 2) ? wb : (p0 + 76);  // l=19 edge

    // ---- fused loop: single chain; 8 waves/SIMD hide the serial chain ----
    f16x4 H = {};
    #pragma unroll
    for (int l = 0; l < LSEQ; ++l) {
        const f16x8 Al = (l == 0) ? A1_0 : (l == LSEQ - 1) ? A1_19 : A1;
        const uint* aL = (l == 0) ? a0 : (l == LSEQ - 1) ? aL19 : (p0 + 4 * l);
        UB128 B1;
        B1.q = *(const uint4*)aL;
        f32x4 a1 = __builtin_amdgcn_mfma_f32_16x16x32_f16(Al, B1.v, zero4, 0, 0, 0);
        UB64 B2;
        B2.p[0] = __builtin_amdgcn_cvt_pkrtz(fmaxf(a1[0], 0.f), fmaxf(a1[1], 0.f));
        B2.p[1] = __builtin_amdgcn_cvt_pkrtz(fmaxf(a1[2], 0.f), fmaxf(a1[3], 0.f));
        f32x4 a2 = __builtin_amdgcn_mfma_f32_16x16x16f16(A2, B2.v, rbp, 0, 0, 0);
        a2 = __builtin_amdgcn_mfma_f32_16x16x16f16(AU, H, a2, 0, 0, 0);
        float t0 = __builtin_amdgcn_rcpf(1.f + __builtin_amdgcn_exp2f(a2[0]));
        float t1 = __builtin_amdgcn_rcpf(1.f + __builtin_amdgcn_exp2f(a2[1]));
        float t2 = __builtin_amdgcn_rcpf(1.f + __builtin_amdgcn_exp2f(a2[2]));
        float t3 = __builtin_amdgcn_rcpf(1.f + __builtin_amdgcn_exp2f(a2[3]));
        UB64 Hn;
        Hn.p[0] = __builtin_amdgcn_cvt_pkrtz(fmaf(-2.f, t0, 1.f), fmaf(-2.f, t1, 1.f));
        Hn.p[1] = __builtin_amdgcn_cvt_pkrtz(fmaf(-2.f, t2, 1.f), fmaf(-2.f, t3, 1.f));
        H = Hn.v;
    }

    // ---- head via MFMA ----
    f32x4 a3 = __builtin_amdgcn_mfma_f32_16x16x16f16(A3, H, c3, 0, 0, 0);
    float part = 0.f;
    #pragma unroll
    for (int r = 0; r < 4; ++r)
        part = fmaf(fmaxf(a3[r], 0.f), ow[r], part);
    part += __shfl_xor(part, 16);
    part += __shfl_xor(part, 32);
    if (lane < 16)
        out[BE + wave * 16 + b16] = part + ob;
}

extern "C" void kernel_launch(void* const* d_in, const int* in_sizes, int n_in,
                              void* d_out, int out_size, void* d_ws, size_t ws_size,
                              hipStream_t stream) {
    const float* x      = (const float*)d_in[0];
    const float* conv_w = (const float*)d_in[1];
    const float* conv_b = (const float*)d_in[2];
    const float* rnn_w  = (const float*)d_in[3];
    const float* rnn_u  = (const float*)d_in[4];
    const float* rnn_b  = (const float*)d_in[5];
    const float* d1_w   = (const float*)d_in[6];
    const float* d1_b   = (const float*)d_in[7];
    const float* out_w  = (const float*)d_in[8];
    const float* out_b  = (const float*)d_in[9];
    float* out = (float*)d_out;

    const int B = out_size;                 // 262144
    const int grid = B / 32;                // 8192 blocks (2 waves each)
    hybrid_fwd<<<grid, BLK, 0, stream>>>(x, conv_w, conv_b, rnn_w, rnn_u, rnn_b,
                                         d1_w, d1_b, out_w, out_b, out);
}

// Round 24
// 39.151 us; speedup vs baseline: 1.0805x; 1.0805x over previous
//
#include <hip/hip_runtime.h>

// SimpleHybridModel via MFMA, all-transposed chaining:
//  conv1d(k=3,SAME,relu) -> SimpleRNN(16,tanh) -> dense(8,relu) -> dense(1)
//
// FINAL (restore of R22, session best: 39.1us, absmax 2.44e-4).
// Design summary (ladder 4025 -> 39.1us):
//  - All-transposed MFMA chaining: conv (16x16x32), rnn_w/rnn_u (16x16x16),
//    head (16x16x16) — each stage's D-fragment layout == next stage's
//    B-fragment layout; zero lane shuffles in the loop.
//  - Weights register-resident as A-fragments, loaded once; conv bias rides
//    the MFMA (A1[k=31] = conv_b vs dummy-1.0 half in every row).
//  - Pad-free 20-slot f16 element tile (320B): 32 elems = 10240B EXACT ->
//    16 blocks/CU (LDS cap) = 512 resident elems (the validated lever).
//    SAME-padding via A-operand zeroing (A1_0 at l=0, A1_19 at l=19);
//    OOB edge lanes redirect to in-bounds addresses (annihilated by zero A).
//  - Single-wave blocks, no __syncthreads (lgkmcnt fence + sched_barrier).
//  - 2 independent recurrence chains/lane (ILP for the serial MFMA+tanh).
//  - tanh = 1 - 2*rcp(1+exp2(a)) with 2*log2e folded into A2/AU/rnn_b.
// Mapped-flat alternatives: waves/CU 32 (worse), 1/4 chains (worse),
// pipelining (compiler sinks loads), staging variants (±5%), barriers
// (neutral). Feed efficiency ~60% of pure-HBM floor; the conversion in the
// staging path precludes async global->LDS at HIP level.

#define BLK 64
#define LSEQ 20
#define EPW 80              // dwords per element: 20 slots * 4 (320 B)
#define LOG2E2 2.8853900817779268f

typedef _Float16 f16;
typedef __fp16   fp16x2 __attribute__((ext_vector_type(2)));
typedef _Float16 f16x4 __attribute__((ext_vector_type(4)));
typedef _Float16 f16x8 __attribute__((ext_vector_type(8)));
typedef float    f32x4 __attribute__((ext_vector_type(4)));

union UB128 { uint4 q; f16x8 v; };
union UB64  { f16x4 v; fp16x2 p[2]; };
union HU    { fp16x2 p; uint u; };

__global__ __launch_bounds__(BLK, 4) void hybrid_fwd(
    const float* __restrict__ x,
    const float* __restrict__ conv_w, const float* __restrict__ conv_b,
    const float* __restrict__ rnn_w,  const float* __restrict__ rnn_u,
    const float* __restrict__ rnn_b,
    const float* __restrict__ d1_w,   const float* __restrict__ d1_b,
    const float* __restrict__ out_w,  const float* __restrict__ out_b,
    float* __restrict__ out)
{
    __shared__ __align__(16) uint xs[32 * EPW];   // 10240 B EXACT (16/CU)

    const int lane = threadIdx.x;                 // single wave
    const int b16  = lane & 15, g = lane >> 4;
    const long BE  = (long)blockIdx.x * 32;       // block's first elem

    // ---- weight fragments FIRST (VMEM latency overlaps staging below) ----
    f16x8 A1;
    #pragma unroll
    for (int t = 0; t < 8; ++t) {
        float wv = conv_w[min(g * 7 + t, 20) * 16 + b16];
        float sel = (g < 3 && t < 7) ? wv
                  : ((g == 3 && t == 7) ? conv_b[b16] : 0.f);
        A1[t] = (f16)sel;
    }
    const f16x8 A1z = {};
    const f16x8 A1_0  = (g == 0) ? A1z : A1;   // l=0:  row -1 contribution = 0
    const f16x8 A1_19 = (g == 2) ? A1z : A1;   // l=19: row 20 contribution = 0
    f16x4 A2, AU;
    f32x4 rbp;
    #pragma unroll
    for (int t = 0; t < 4; ++t) {
        A2[t]  = (f16)(LOG2E2 * rnn_w[(4 * g + t) * 16 + b16]);
        AU[t]  = (f16)(LOG2E2 * rnn_u[(4 * g + t) * 16 + b16]);
        rbp[t] = LOG2E2 * rnn_b[4 * g + t];
    }
    f16x4 A3;
    f32x4 c3;
    #pragma unroll
    for (int t = 0; t < 4; ++t) {
        int j = 4 * g + t;
        A3[t] = (f16)(b16 < 8 ? d1_w[j * 8 + b16] : 0.f);
        c3[t] = d1_b[min(j, 7)];
    }
    float ow[4];
    #pragma unroll
    for (int r = 0; r < 4; ++r)
        ow[r] = (g < 2) ? out_w[min(4 * g + r, 7)] : 0.f;
    const float ob = out_b[0];
    const f32x4 zero4 = {0.f, 0.f, 0.f, 0.f};

    // ---- stage x: 2 lanes/elem, rows -> slot r (no pad) ----
    {
        const int e = lane & 31;                  // staged elem
        const int h = lane >> 5;                  // half: rows 10h..10h+9
        const float2* sp = (const float2*)(x + (BE + e) * 140 + h * 70);
        float2 f2[35];
        #pragma unroll
        for (int i = 0; i < 35; ++i) f2[i] = sp[i];
        const float* f = (const float*)f2;        // static-indexed
        uint* eb = xs + e * EPW;
        #pragma unroll
        for (int i = 0; i < 10; ++i) {            // row r = 10h+i -> slot r
            HU h0, h1, h2, h3;
            h0.p = __builtin_amdgcn_cvt_pkrtz(f[7 * i + 0], f[7 * i + 1]);
            h1.p = __builtin_amdgcn_cvt_pkrtz(f[7 * i + 2], f[7 * i + 3]);
            h2.p = __builtin_amdgcn_cvt_pkrtz(f[7 * i + 4], f[7 * i + 5]);
            h3.p = __builtin_amdgcn_cvt_pkrtz(f[7 * i + 6], 1.0f);   // dummy
            uint4 val; val.x = h0.u; val.y = h1.u; val.z = h2.u; val.w = h3.u;
            *(uint4*)(eb + 4 * (10 * h + i)) = val;   // 16B aligned
        }
    }

    // ---- wave-local fence (single-wave block; rule #18) ----
    asm volatile("s_waitcnt lgkmcnt(0)" ::: "memory");
    __builtin_amdgcn_sched_barrier(0);

    // ---- read pointers: tap g reads slot l-1+g (g<=2); g=3 reads slot l ----
    const int d = (g == 3) ? 0 : (g - 1);         // slot delta vs l
    const uint* p0 = xs + b16 * EPW + 4 * d;             // chain A (elem b16)
    const uint* p1 = xs + (16 + b16) * EPW + 4 * d;      // chain B (elem 16+b16)
    // OOB edge redirects (content annihilated by A1_0 / A1_19):
    const uint* q0a  = (b16 == 0  && g == 0) ? xs : p0;                  // l=0, chain A
    const uint* q19b = (b16 == 15 && g == 2) ? (xs + 31 * EPW) : (p1 + 76); // l=19, chain B

    // ---- Phase A: conv + relu, both chains, full unroll ----
    f16x4 B2sA[LSEQ], B2sB[LSEQ];
    #pragma unroll
    for (int l = 0; l < LSEQ; ++l) {
        const f16x8 Al = (l == 0) ? A1_0 : (l == LSEQ - 1) ? A1_19 : A1;
        const uint* aA = (l == 0) ? q0a : (p0 + 4 * l);
        const uint* aB = (l == LSEQ - 1) ? q19b : (p1 + 4 * l);
        UB128 B1a, B1b;
        B1a.q = *(const uint4*)aA;
        B1b.q = *(const uint4*)aB;
        f32x4 a1a = __builtin_amdgcn_mfma_f32_16x16x32_f16(Al, B1a.v, zero4, 0, 0, 0);
        f32x4 a1b = __builtin_amdgcn_mfma_f32_16x16x32_f16(Al, B1b.v, zero4, 0, 0, 0);
        UB64 Ba, Bb;
        Ba.p[0] = __builtin_amdgcn_cvt_pkrtz(fmaxf(a1a[0], 0.f), fmaxf(a1a[1], 0.f));
        Ba.p[1] = __builtin_amdgcn_cvt_pkrtz(fmaxf(a1a[2], 0.f), fmaxf(a1a[3], 0.f));
        Bb.p[0] = __builtin_amdgcn_cvt_pkrtz(fmaxf(a1b[0], 0.f), fmaxf(a1b[1], 0.f));
        Bb.p[1] = __builtin_amdgcn_cvt_pkrtz(fmaxf(a1b[2], 0.f), fmaxf(a1b[3], 0.f));
        B2sA[l] = Ba.v;
        B2sB[l] = Bb.v;
    }

    // ---- Phase B: two independent serial recurrences, interleaved ----
    f16x4 H0 = {}, H1 = {};
    #pragma unroll
    for (int l = 0; l < LSEQ; ++l) {
        f32x4 a20 = __builtin_amdgcn_mfma_f32_16x16x16f16(A2, B2sA[l], rbp, 0, 0, 0);
        f32x4 a21 = __builtin_amdgcn_mfma_f32_16x16x16f16(A2, B2sB[l], rbp, 0, 0, 0);
        a20 = __builtin_amdgcn_mfma_f32_16x16x16f16(AU, H0, a20, 0, 0, 0);
        a21 = __builtin_amdgcn_mfma_f32_16x16x16f16(AU, H1, a21, 0, 0, 0);
        float t00 = __builtin_amdgcn_rcpf(1.f + __builtin_amdgcn_exp2f(a20[0]));
        float t01 = __builtin_amdgcn_rcpf(1.f + __builtin_amdgcn_exp2f(a20[1]));
        float t02 = __builtin_amdgcn_rcpf(1.f + __builtin_amdgcn_exp2f(a20[2]));
        float t03 = __builtin_amdgcn_rcpf(1.f + __builtin_amdgcn_exp2f(a20[3]));
        float t10 = __builtin_amdgcn_rcpf(1.f + __builtin_amdgcn_exp2f(a21[0]));
        float t11 = __builtin_amdgcn_rcpf(1.f + __builtin_amdgcn_exp2f(a21[1]));
        float t12 = __builtin_amdgcn_rcpf(1.f + __builtin_amdgcn_exp2f(a21[2]));
        float t13 = __builtin_amdgcn_rcpf(1.f + __builtin_amdgcn_exp2f(a21[3]));
        UB64 Hn0, Hn1;
        Hn0.p[0] = __builtin_amdgcn_cvt_pkrtz(fmaf(-2.f, t00, 1.f), fmaf(-2.f, t01, 1.f));
        Hn0.p[1] = __builtin_amdgcn_cvt_pkrtz(fmaf(-2.f, t02, 1.f), fmaf(-2.f, t03, 1.f));
        Hn1.p[0] = __builtin_amdgcn_cvt_pkrtz(fmaf(-2.f, t10, 1.f), fmaf(-2.f, t11, 1.f));
        Hn1.p[1] = __builtin_amdgcn_cvt_pkrtz(fmaf(-2.f, t12, 1.f), fmaf(-2.f, t13, 1.f));
        H0 = Hn0.v;
        H1 = Hn1.v;
    }

    // ---- head via MFMA ----
    f32x4 a30 = __builtin_amdgcn_mfma_f32_16x16x16f16(A3, H0, c3, 0, 0, 0);
    f32x4 a31 = __builtin_amdgcn_mfma_f32_16x16x16f16(A3, H1, c3, 0, 0, 0);
    float p0h = 0.f, p1h = 0.f;
    #pragma unroll
    for (int r = 0; r < 4; ++r) {
        p0h = fmaf(fmaxf(a30[r], 0.f), ow[r], p0h);
        p1h = fmaf(fmaxf(a31[r], 0.f), ow[r], p1h);
    }
    p0h += __shfl_xor(p0h, 16); p0h += __shfl_xor(p0h, 32);
    p1h += __shfl_xor(p1h, 16); p1h += __shfl_xor(p1h, 32);
    if (lane < 16) {
        out[BE + b16]      = p0h + ob;
        out[BE + 16 + b16] = p1h + ob;
    }
}

extern "C" void kernel_launch(void* const* d_in, const int* in_sizes, int n_in,
                              void* d_out, int out_size, void* d_ws, size_t ws_size,
                              hipStream_t stream) {
    const float* x      = (const float*)d_in[0];
    const float* conv_w = (const float*)d_in[1];
    const float* conv_b = (const float*)d_in[2];
    const float* rnn_w  = (const float*)d_in[3];
    const float* rnn_u  = (const float*)d_in[4];
    const float* rnn_b  = (const float*)d_in[5];
    const float* d1_w   = (const float*)d_in[6];
    const float* d1_b   = (const float*)d_in[7];
    const float* out_w  = (const float*)d_in[8];
    const float* out_b  = (const float*)d_in[9];
    float* out = (float*)d_out;

    const int B = out_size;                 // 262144
    const int grid = B / 32;                // 8192 single-wave blocks
    hybrid_fwd<<<grid, BLK, 0, stream>>>(x, conv_w, conv_b, rnn_w, rnn_u, rnn_b,
                                         d1_w, d1_b, out_w, out_b, out);
}